// Round 15
// baseline (334.691 us; speedup 1.0000x reference)
//
#include <hip/hip_runtime.h>
#include <hip/hip_bf16.h>

// B=128, N=50, NB=32, K=8, H=64, D=512. sites=6400, neighbor rows=204800.
// UNFUSED this round:
//   gemm_tile<SWZ>: 128x256 tile, BK=32, 4 waves (wave=128x64), double-buffered
//     LDS, r8-verified counted-vmcnt ledger (8 DMAs/wave/step, vmcnt(8)).
//     XCD pair-swizzle puts both col-blocks of an A panel on one XCD.
//     Epilogue: bias+ReLU+l2norm(64-col groups) -> z bf16 to HBM.
//   routing_iters: round-4 verified kernel, verbatim.

#define D_DIM 512
#define BK 32
#define KSTEPS 16

typedef __attribute__((ext_vector_type(8))) short short8;
typedef __attribute__((ext_vector_type(4))) float f32x4;

static __device__ __forceinline__ short f2bf(float f) {
    __bf16 b = (__bf16)f;
    return __builtin_bit_cast(short, b);
}
static __device__ __forceinline__ float bf2f(short s) {
    unsigned u = ((unsigned)(unsigned short)s) << 16;
    return __builtin_bit_cast(float, u);
}
static __device__ __forceinline__ void gload_lds16(const void* g, void* l) {
    __builtin_amdgcn_global_load_lds(
        (const __attribute__((address_space(1))) void*)g,
        (__attribute__((address_space(3))) void*)l, 16, 0, 0);
}

__global__ __launch_bounds__(256) void wconv(const float* __restrict__ W,
                                             short* __restrict__ Wb) {
    const int i = (blockIdx.x * 256 + threadIdx.x) * 8;
    const float4 v0 = *reinterpret_cast<const float4*>(W + i);
    const float4 v1 = *reinterpret_cast<const float4*>(W + i + 4);
    short8 o;
    o[0] = f2bf(v0.x); o[1] = f2bf(v0.y); o[2] = f2bf(v0.z); o[3] = f2bf(v0.w);
    o[4] = f2bf(v1.x); o[5] = f2bf(v1.y); o[6] = f2bf(v1.z); o[7] = f2bf(v1.w);
    *reinterpret_cast<short8*>(Wb + i) = o;
}

// 256 threads = 4 waves; wave w -> rows [0,128) x cols [64w, 64w+64) of tile.
// lAf32[2]: [128][32] f32 (16 KB each); row = 8 x 16B slots, P=(G+row)&7.
// lB[2]:    [256][32] bf16 (16 KB each); row = 4 x 16B slots, P=(G+(row>>1))&3.
template <bool SWZ>
__global__ __launch_bounds__(256, 2) void gemm_tile(
    const float* __restrict__ A,     // [R,512] fp32
    const short* __restrict__ Wb,    // [512,512] bf16
    const float* __restrict__ bias,  // [512]
    short* __restrict__ Z)           // [R,512] bf16, l2-normalized 64-groups
{
    __shared__ __align__(16) char smem[65536];
    float* const lAf32 = (float*)smem;           // [2][4096] f32 (32 KB)
    short* const lB = (short*)(smem + 32768);    // [2][8192] bf16 (32 KB)

    int id = blockIdx.x;
    if (SWZ) id = (id & 7) * ((int)gridDim.x >> 3) + (id >> 3);
    const size_t row0 = (size_t)(id >> 1) * 128;
    const int col0 = (id & 1) * 256;

    const int t = threadIdx.x;
    const int lane = t & 63;
    const int wid = t >> 6;
    const int l15 = lane & 15;
    const int q = lane >> 4;

    // 8 DMAs per wave per step: 4 B-chunks + 4 A-chunks (1024 B each).
    auto stage = [&](int step, int buf) {
        const int k0 = (step < KSTEPS ? step : 0) * BK;
        #pragma unroll
        for (int i = 0; i < 4; ++i) {            // B: chunk = 16 rows x 64 B
            const int c = wid * 4 + i;
            const int r = c * 16 + (lane >> 2);
            const int g = ((lane & 3) - (r >> 1)) & 3;
            gload_lds16(Wb + (size_t)(col0 + r) * D_DIM + k0 + g * 8,
                        lB + buf * 8192 + c * 512);
        }
        #pragma unroll
        for (int i = 0; i < 4; ++i) {            // A: chunk = 8 rows x 128 B
            const int c = wid * 4 + i;
            const int r = c * 8 + (lane >> 3);
            const int g = ((lane & 7) - (lane >> 3)) & 7;
            gload_lds16(A + (row0 + r) * D_DIM + k0 + g * 4,
                        lAf32 + buf * 4096 + c * 256);
        }
    };

    f32x4 acc[8][4] = {};
    auto compute = [&](int buf) {
        short8 af[8], bfr[4];
        #pragma unroll
        for (int m = 0; m < 8; ++m) {
            const int r = m * 16 + l15;
            const float* rowp = lAf32 + buf * 4096 + r * 32;
            const int P0 = (2 * q + r) & 7;
            const int P1 = (2 * q + 1 + r) & 7;
            const f32x4 a0 = *reinterpret_cast<const f32x4*>(rowp + P0 * 4);
            const f32x4 a1 = *reinterpret_cast<const f32x4*>(rowp + P1 * 4);
            short8 f;
            f[0] = f2bf(a0[0]); f[1] = f2bf(a0[1]);
            f[2] = f2bf(a0[2]); f[3] = f2bf(a0[3]);
            f[4] = f2bf(a1[0]); f[5] = f2bf(a1[1]);
            f[6] = f2bf(a1[2]); f[7] = f2bf(a1[3]);
            af[m] = f;
        }
        #pragma unroll
        for (int n = 0; n < 4; ++n) {
            const int rb = wid * 64 + n * 16 + l15;
            bfr[n] = *reinterpret_cast<const short8*>(
                lB + buf * 8192 + rb * 32 + ((q + (rb >> 1)) & 3) * 8);
        }
        #pragma unroll
        for (int m = 0; m < 8; ++m)
            #pragma unroll
            for (int n = 0; n < 4; ++n)
                acc[m][n] = __builtin_amdgcn_mfma_f32_16x16x32_bf16(
                    af[m], bfr[n], acc[m][n], 0, 0, 0);
    };

    // ---- pipeline: r8-verified ledger (counted vmcnt, single op type)
    stage(0, 0);
    stage(1, 1);
    asm volatile("s_waitcnt vmcnt(8)" ::: "memory");    // stage0 (+scalars) done
    __builtin_amdgcn_s_barrier();
    #pragma unroll
    for (int tk = 0; tk < KSTEPS; ++tk) {
        compute(tk & 1);
        asm volatile("s_waitcnt lgkmcnt(0)" ::: "memory");  // reads consumed
        __builtin_amdgcn_s_barrier();                       // buf tk&1 free
        stage(tk + 2, tk & 1);                              // overwrite it
        asm volatile("s_waitcnt vmcnt(8)" ::: "memory");    // stage(tk+1) done
        __builtin_amdgcn_s_barrier();                       // visible to all
    }
    asm volatile("s_waitcnt vmcnt(0)" ::: "memory");        // drain tail junk
    __builtin_amdgcn_s_barrier();

    // ---- epilogue: bias + ReLU + l2norm over the wave's 64-col group.
    const int cb = col0 + wid * 64 + l15;
    float bcol[4];
    #pragma unroll
    for (int n = 0; n < 4; ++n) bcol[n] = bias[cb + n * 16];

    #pragma unroll
    for (int m = 0; m < 8; ++m) {
        #pragma unroll
        for (int r = 0; r < 4; ++r) {
            float v[4];
            float ss = 0.0f;
            #pragma unroll
            for (int n = 0; n < 4; ++n) {
                v[n] = fmaxf(acc[m][n][r] + bcol[n], 0.0f);
                ss = fmaf(v[n], v[n], ss);
            }
            ss += __shfl_xor(ss, 1);
            ss += __shfl_xor(ss, 2);
            ss += __shfl_xor(ss, 4);
            ss += __shfl_xor(ss, 8);
            const float inv = 1.0f / fmaxf(sqrtf(ss), 1e-12f);
            const size_t orow = row0 + m * 16 + q * 4 + r;
            #pragma unroll
            for (int n = 0; n < 4; ++n)
                Z[orow * D_DIM + cb + n * 16] = f2bf(v[n] * inv);
        }
    }
}

// Round-4 verified routing kernel (verbatim): one block per site,
// nz [32][512] fp32 in LDS sourced from bf16; thread owns elems {t, t+256}.
__global__ __launch_bounds__(256) void routing_iters(
    const short* __restrict__ NZ,   // [sites,32,512] bf16 normalized
    const short* __restrict__ S,    // [sites,512] bf16 normalized
    const int* __restrict__ miter_ptr,
    float* __restrict__ out)        // [sites,512]
{
    __shared__ float nz[32 * 512];
    __shared__ float u[512];
    __shared__ float p[256];

    const int site = blockIdx.x;
    const int t = threadIdx.x;
    const int lane = t & 63;

    const short8* src = reinterpret_cast<const short8*>(NZ + (size_t)site * 32 * D_DIM);
    #pragma unroll
    for (int i = 0; i < 8; ++i) {
        const short8 c = src[t + 256 * i];
        const int base = (t + 256 * i) * 8;
        float4 f0, f1;
        f0.x = bf2f(c[0]); f0.y = bf2f(c[1]); f0.z = bf2f(c[2]); f0.w = bf2f(c[3]);
        f1.x = bf2f(c[4]); f1.y = bf2f(c[5]); f1.z = bf2f(c[6]); f1.w = bf2f(c[7]);
        *reinterpret_cast<float4*>(nz + base) = f0;
        *reinterpret_cast<float4*>(nz + base + 4) = f1;
    }

    const int e0 = t, e1 = t + 256;
    const float s0 = bf2f(S[(size_t)site * D_DIM + e0]);
    const float s1 = bf2f(S[(size_t)site * D_DIM + e1]);
    const int miter = *miter_ptr;

    __syncthreads();

    float a0 = 0.0f, a1 = 0.0f;
    for (int m = 0; m < 32; ++m) {
        a0 += nz[m * D_DIM + e0];
        a1 += nz[m * D_DIM + e1];
    }
    float v0 = fmaf(a0, 0.125f, s0);
    float v1 = fmaf(a1, 0.125f, s1);

    const int m_ = t >> 3;
    const int k_ = t & 7;
    const int k0 = e0 >> 6;
    const int k1 = e1 >> 6;

    for (int it = 1; it < miter; ++it) {
        float ss0 = v0 * v0, ss1 = v1 * v1;
        #pragma unroll
        for (int off = 32; off >= 1; off >>= 1) {
            ss0 += __shfl_xor(ss0, off);
            ss1 += __shfl_xor(ss1, off);
        }
        v0 *= 1.0f / fmaxf(sqrtf(ss0), 1e-12f);
        v1 *= 1.0f / fmaxf(sqrtf(ss1), 1e-12f);
        u[e0] = v0;
        u[e1] = v1;
        __syncthreads();

        float dot = 0.0f;
        const int base = m_ * D_DIM + k_ * 64;
        const int ub = k_ * 64;
        #pragma unroll
        for (int i = 0; i < 64; ++i) {
            const int hh = (i + lane) & 63;
            dot = fmaf(nz[base + hh], u[ub + hh], dot);
        }
        float mx = dot;
        mx = fmaxf(mx, __shfl_xor(mx, 1));
        mx = fmaxf(mx, __shfl_xor(mx, 2));
        mx = fmaxf(mx, __shfl_xor(mx, 4));
        const float pe = __expf(dot - mx);
        float psum = pe;
        psum += __shfl_xor(psum, 1);
        psum += __shfl_xor(psum, 2);
        psum += __shfl_xor(psum, 4);
        p[t] = pe / psum;
        __syncthreads();

        a0 = 0.0f; a1 = 0.0f;
        for (int m = 0; m < 32; ++m) {
            a0 = fmaf(nz[m * D_DIM + e0], p[m * 8 + k0], a0);
            a1 = fmaf(nz[m * D_DIM + e1], p[m * 8 + k1], a1);
        }
        v0 = s0 + a0;
        v1 = s1 + a1;
        __syncthreads();
    }

    out[(size_t)site * D_DIM + e0] = fmaxf(v0, 0.0f);
    out[(size_t)site * D_DIM + e1] = fmaxf(v1, 0.0f);
}

extern "C" void kernel_launch(void* const* d_in, const int* in_sizes, int n_in,
                              void* d_out, int out_size, void* d_ws, size_t ws_size,
                              hipStream_t stream) {
    const float* self_v  = (const float*)d_in[0];   // [6400,512]
    const float* neigh_v = (const float*)d_in[1];   // [204800,512]
    const float* W1      = (const float*)d_in[2];   // [512,512]
    const float* b1      = (const float*)d_in[3];   // [512]
    const int*   miter   = (const int*)d_in[4];
    float* out = (float*)d_out;

    const int sites = in_sizes[0] / D_DIM;          // 6400
    const int nrows = in_sizes[1] / D_DIM;          // 204800

    short* z  = (short*)d_ws;                       // [nrows,512] bf16
    short* s  = z + (size_t)nrows * D_DIM;          // [sites,512] bf16
    short* Wb = s + (size_t)sites * D_DIM;          // [512,512] bf16

    wconv<<<dim3(D_DIM * D_DIM / (256 * 8)), dim3(256), 0, stream>>>(W1, Wb);
    // self: 6400/128 = 50 panels x 2 col-blocks = 100 blocks (no swizzle)
    gemm_tile<false><<<dim3(sites / 128 * 2), dim3(256), 0, stream>>>(
        self_v, Wb, b1, s);
    // neighbor: 204800/128 = 1600 panels x 2 = 3200 blocks (XCD pair-swizzle)
    gemm_tile<true><<<dim3(nrows / 128 * 2), dim3(256), 0, stream>>>(
        neigh_v, Wb, b1, z);
    routing_iters<<<dim3(sites), dim3(256), 0, stream>>>(z, s, miter, out);
}

// Round 16
// 249.590 us; speedup vs baseline: 1.3410x; 1.3410x over previous
//
#include <hip/hip_runtime.h>
#include <hip/hip_bf16.h>

// B=128, N=50, NB=32, K=8, H=64, D=512. sites=6400, neighbor rows=204800.
// Fused: per block, 64 neighbor rows (=2 sites) GEMM (bf16 MFMA) into LDS zbuf
// (bf16), then 3 routing iterations in-block, write fp32 out. nz never hits HBM.
// Staging: SINGLE-TYPE global_load_lds for BOTH A (raw fp32) and B (bf16),
// counted s_waitcnt vmcnt(10) + raw s_barrier (m201 pattern) — loads stay in
// flight across barriers. A converted fp32->bf16 at fragment read.
// [Session-best structure, verified twice at 251.4/251.5 µs.]

#define D_DIM 512
#define BM 64
#define BK 32
#define KSTEPS 16

typedef __attribute__((ext_vector_type(8))) short short8;
typedef __attribute__((ext_vector_type(4))) short short4v;
typedef __attribute__((ext_vector_type(4))) float f32x4;

static __device__ __forceinline__ short f2bf(float f) {
    __bf16 b = (__bf16)f;
    return __builtin_bit_cast(short, b);
}
static __device__ __forceinline__ float bf2f(short s) {
    unsigned u = ((unsigned)(unsigned short)s) << 16;
    return __builtin_bit_cast(float, u);
}
static __device__ __forceinline__ void gload_lds16(const void* g, void* l) {
    __builtin_amdgcn_global_load_lds(
        (const __attribute__((address_space(1))) void*)g,
        (__attribute__((address_space(3))) void*)l, 16, 0, 0);
}

__global__ __launch_bounds__(256) void wconv(const float* __restrict__ W,
                                             short* __restrict__ Wb) {
    const int i = (blockIdx.x * 256 + threadIdx.x) * 8;
    const float4 v0 = *reinterpret_cast<const float4*>(W + i);
    const float4 v1 = *reinterpret_cast<const float4*>(W + i + 4);
    short8 o;
    o[0] = f2bf(v0.x); o[1] = f2bf(v0.y); o[2] = f2bf(v0.z); o[3] = f2bf(v0.w);
    o[4] = f2bf(v1.x); o[5] = f2bf(v1.y); o[6] = f2bf(v1.z); o[7] = f2bf(v1.w);
    *reinterpret_cast<short8*>(Wb + i) = o;
}

// 256 threads = 4 waves; wave w -> 64 rows x cols [128w,128w+128).
// lAf32[2]: [64][32] f32 (8 KB each) via DMA; row = 8 x 16B slots, phys
//   slot p=(g+2*(r&3))&7 (pair-preserving rotation -> 4-way read residual).
// lB[2]: [512][32] bf16 (32 KB each) via DMA; row = 4 x 16B slots, phys
//   slot p=(g+(r>>1))&3 (conflict-free reads).
template <bool FUSED>
__global__ __launch_bounds__(256, 2) void gemm_route(
    const float* __restrict__ A,     // [R,512] fp32
    const short* __restrict__ Wb,    // [512,512] bf16
    const float* __restrict__ bias,  // [512]
    short* __restrict__ Zs,          // !FUSED: s output bf16
    const short* __restrict__ S,     // FUSED: s input bf16
    const int* __restrict__ miter_ptr,
    float* __restrict__ out)         // FUSED: [sites,512] fp32
{
    __shared__ __align__(16) char smem[81920];
    float* const lAf32 = (float*)smem;           // [2][2048] f32  (16 KB)
    short* const lB = (short*)(smem + 16384);    // [2][16384] bf16 (64 KB)

    const int t = threadIdx.x;
    const int lane = t & 63;
    const int wid = t >> 6;
    const size_t row0 = (size_t)blockIdx.x * BM;
    const int wc = wid * 128;

    // hoisted scalars: issued before the first asm fence; ledger is robust to
    // their placement (each counted wait retires all but the newest 10).
    const int cb = wc + (lane & 15);
    float bcol[8];
    #pragma unroll
    for (int n = 0; n < 8; ++n) bcol[n] = bias[cb + n * 16];
    int miter = 0;
    if (FUSED) miter = *miter_ptr;

    // 10 DMAs per wave per step: 8 B-chunks + 2 A-chunks (1024 B each).
    auto stage = [&](int step, int buf) {
        const int k0 = (step < KSTEPS ? step : 0) * BK;
        #pragma unroll
        for (int i = 0; i < 8; ++i) {            // B: chunk = 16 rows x 64 B
            const int c = wid * 8 + i;
            const int r = c * 16 + (lane >> 2);
            const int g = ((lane & 3) - (r >> 1)) & 3;
            gload_lds16(Wb + (size_t)r * D_DIM + k0 + g * 8,
                        lB + buf * 16384 + c * 512);
        }
        #pragma unroll
        for (int i = 0; i < 2; ++i) {            // A: chunk = 8 rows x 128 B
            const int c = wid * 2 + i;
            const int r = c * 8 + (lane >> 3);
            const int g = ((lane & 7) - 2 * (r & 3)) & 7;
            gload_lds16(A + (row0 + r) * D_DIM + k0 + g * 4,
                        lAf32 + buf * 2048 + c * 256);
        }
    };

    f32x4 acc[4][8] = {};
    auto compute = [&](int buf) {
        const int q = lane >> 4;                 // k 16B-slot pair index
        short8 af[4], bfr[8];
        #pragma unroll
        for (int m = 0; m < 4; ++m) {
            const int r = m * 16 + (lane & 15);
            const float* ap = lAf32 + buf * 2048 + r * 32 + ((q + (r & 3)) & 3) * 8;
            const f32x4 a0 = *reinterpret_cast<const f32x4*>(ap);
            const f32x4 a1 = *reinterpret_cast<const f32x4*>(ap + 4);
            short8 f;
            f[0] = f2bf(a0[0]); f[1] = f2bf(a0[1]);
            f[2] = f2bf(a0[2]); f[3] = f2bf(a0[3]);
            f[4] = f2bf(a1[0]); f[5] = f2bf(a1[1]);
            f[6] = f2bf(a1[2]); f[7] = f2bf(a1[3]);
            af[m] = f;
        }
        #pragma unroll
        for (int n = 0; n < 8; ++n) {
            const int r = wc + n * 16 + (lane & 15);
            bfr[n] = *reinterpret_cast<const short8*>(
                lB + buf * 16384 + r * 32 + ((q + (r >> 1)) & 3) * 8);
        }
        #pragma unroll
        for (int m = 0; m < 4; ++m)
            #pragma unroll
            for (int n = 0; n < 8; ++n)
                acc[m][n] = __builtin_amdgcn_mfma_f32_16x16x32_bf16(
                    af[m], bfr[n], acc[m][n], 0, 0, 0);
    };

    // ---- pipeline: counted vmcnt, single op type, loads fly across barriers
    stage(0, 0);
    stage(1, 1);
    asm volatile("s_waitcnt vmcnt(10)" ::: "memory");   // stage0 (+scalars) done
    __builtin_amdgcn_s_barrier();
    #pragma unroll
    for (int tk = 0; tk < KSTEPS; ++tk) {
        compute(tk & 1);
        asm volatile("s_waitcnt lgkmcnt(0)" ::: "memory");  // reads consumed
        __builtin_amdgcn_s_barrier();                       // buf tk&1 free
        stage(tk + 2, tk & 1);                              // overwrite it
        asm volatile("s_waitcnt vmcnt(10)" ::: "memory");   // stage(tk+1) done
        __builtin_amdgcn_s_barrier();                       // visible to all
    }
    asm volatile("s_waitcnt vmcnt(0)" ::: "memory");        // drain tail junk
    __builtin_amdgcn_s_barrier();

    // ---- epilogue: bias + ReLU + l2norm per 64-col group; z as bf16.
    short* const zbuf = (short*)(smem + 16384);   // aliases lB (free now)
    #pragma unroll
    for (int m = 0; m < 4; ++m) {
        #pragma unroll
        for (int r = 0; r < 4; ++r) {
            float v[8];
            float ssa = 0.0f, ssb = 0.0f;
            #pragma unroll
            for (int n = 0; n < 4; ++n) {
                v[n] = fmaxf(acc[m][n][r] + bcol[n], 0.0f);
                ssa = fmaf(v[n], v[n], ssa);
            }
            #pragma unroll
            for (int n = 4; n < 8; ++n) {
                v[n] = fmaxf(acc[m][n][r] + bcol[n], 0.0f);
                ssb = fmaf(v[n], v[n], ssb);
            }
            ssa += __shfl_xor(ssa, 1); ssb += __shfl_xor(ssb, 1);
            ssa += __shfl_xor(ssa, 2); ssb += __shfl_xor(ssb, 2);
            ssa += __shfl_xor(ssa, 4); ssb += __shfl_xor(ssb, 4);
            ssa += __shfl_xor(ssa, 8); ssb += __shfl_xor(ssb, 8);
            const float inva = 1.0f / fmaxf(sqrtf(ssa), 1e-12f);
            const float invb = 1.0f / fmaxf(sqrtf(ssb), 1e-12f);
            const int orow = m * 16 + (lane >> 4) * 4 + r;   // 0..63
            if (FUSED) {
                #pragma unroll
                for (int n = 0; n < 4; ++n)
                    zbuf[orow * D_DIM + cb + n * 16] = f2bf(v[n] * inva);
                #pragma unroll
                for (int n = 4; n < 8; ++n)
                    zbuf[orow * D_DIM + cb + n * 16] = f2bf(v[n] * invb);
            } else {
                #pragma unroll
                for (int n = 0; n < 4; ++n)
                    Zs[(row0 + orow) * D_DIM + cb + n * 16] = f2bf(v[n] * inva);
                #pragma unroll
                for (int n = 4; n < 8; ++n)
                    Zs[(row0 + orow) * D_DIM + cb + n * 16] = f2bf(v[n] * invb);
            }
        }
    }

    if (!FUSED) return;
    __syncthreads();   // zbuf complete

    // ---- routing (verified): 2 sites/block, 128 threads each.
    float* const scratch = (float*)smem;          // aliases lAf32 (free now)
    const int tt = t & 127;
    const int ssid = t >> 7;
    const size_t site = (size_t)blockIdx.x * 2 + ssid;
    float* const u_ = scratch + ssid * 512;                 // [0, 4096) bytes
    float* const p_ = (float*)(smem + 4096) + ssid * 256;   // [4096, 6144)
    const short* const zr = zbuf + ssid * 32 * D_DIM;

    const int e = tt * 4;
    const int go = tt >> 4;                  // capsule group of owned elems
    const short4v sv = *reinterpret_cast<const short4v*>(S + site * D_DIM + e);
    const float s0 = bf2f(sv[0]), s1 = bf2f(sv[1]);
    const float s2 = bf2f(sv[2]), s3 = bf2f(sv[3]);

    float v0, v1, v2, v3;
    {   // iteration 0: p uniform 1/8
        float a0 = 0, a1 = 0, a2 = 0, a3 = 0;
        for (int m = 0; m < 32; ++m) {
            const short4v z = *reinterpret_cast<const short4v*>(zr + m * D_DIM + e);
            a0 += bf2f(z[0]); a1 += bf2f(z[1]); a2 += bf2f(z[2]); a3 += bf2f(z[3]);
        }
        v0 = fmaf(a0, 0.125f, s0); v1 = fmaf(a1, 0.125f, s1);
        v2 = fmaf(a2, 0.125f, s2); v3 = fmaf(a3, 0.125f, s3);
    }

    const int dm = tt >> 2;                  // neighbor for this thread's dots
    const int ka = (tt & 3) * 2;             // capsule pair

    for (int it = 1; it < miter; ++it) {
        // normalize u per 64-group (16-thread shfl groups, wave-aligned)
        float ssum = v0 * v0 + v1 * v1 + v2 * v2 + v3 * v3;
        ssum += __shfl_xor(ssum, 1);
        ssum += __shfl_xor(ssum, 2);
        ssum += __shfl_xor(ssum, 4);
        ssum += __shfl_xor(ssum, 8);
        const float inv = 1.0f / fmaxf(sqrtf(ssum), 1e-12f);
        v0 *= inv; v1 *= inv; v2 *= inv; v3 *= inv;
        *reinterpret_cast<float4*>(u_ + e) = make_float4(v0, v1, v2, v3);
        __syncthreads();

        // dots: p[dm][ka], p[dm][ka+1]; staggered octet reads
        const short* const za = zr + dm * D_DIM + ka * 64;
        const float* const ua = u_ + ka * 64;
        float da = 0, db = 0;
        #pragma unroll
        for (int j = 0; j < 8; ++j) {
            const int jj = ((j + (tt & 7)) & 7) * 8;
            const short8 zva = *reinterpret_cast<const short8*>(za + jj);
            const short8 zvb = *reinterpret_cast<const short8*>(za + 64 + jj);
            const f32x4 uA0 = *reinterpret_cast<const f32x4*>(ua + jj);
            const f32x4 uA1 = *reinterpret_cast<const f32x4*>(ua + jj + 4);
            const f32x4 uB0 = *reinterpret_cast<const f32x4*>(ua + 64 + jj);
            const f32x4 uB1 = *reinterpret_cast<const f32x4*>(ua + 64 + jj + 4);
            #pragma unroll
            for (int qq = 0; qq < 4; ++qq) {
                da = fmaf(bf2f(zva[qq]), uA0[qq], da);
                da = fmaf(bf2f(zva[qq + 4]), uA1[qq], da);
                db = fmaf(bf2f(zvb[qq]), uB0[qq], db);
                db = fmaf(bf2f(zvb[qq + 4]), uB1[qq], db);
            }
        }
        // softmax over 8 k (4 threads x 2 vals)
        float mx = fmaxf(da, db);
        mx = fmaxf(mx, __shfl_xor(mx, 1));
        mx = fmaxf(mx, __shfl_xor(mx, 2));
        const float ea = __expf(da - mx), eb = __expf(db - mx);
        float sm_ = ea + eb;
        sm_ += __shfl_xor(sm_, 1);
        sm_ += __shfl_xor(sm_, 2);
        const float rs = 1.0f / sm_;
        *reinterpret_cast<float2*>(p_ + dm * 8 + ka) = make_float2(ea * rs, eb * rs);
        __syncthreads();

        // u = s + sum_m z[m]*p[m, go]
        float a0 = 0, a1 = 0, a2 = 0, a3 = 0;
        for (int m = 0; m < 32; ++m) {
            const short4v z = *reinterpret_cast<const short4v*>(zr + m * D_DIM + e);
            const float pm = p_[m * 8 + go];
            a0 = fmaf(bf2f(z[0]), pm, a0); a1 = fmaf(bf2f(z[1]), pm, a1);
            a2 = fmaf(bf2f(z[2]), pm, a2); a3 = fmaf(bf2f(z[3]), pm, a3);
        }
        v0 = s0 + a0; v1 = s1 + a1; v2 = s2 + a2; v3 = s3 + a3;
        // next p_ write is after next norm's barrier -> safe
    }

    *reinterpret_cast<float4*>(out + site * D_DIM + e) =
        make_float4(fmaxf(v0, 0.0f), fmaxf(v1, 0.0f),
                    fmaxf(v2, 0.0f), fmaxf(v3, 0.0f));
}

extern "C" void kernel_launch(void* const* d_in, const int* in_sizes, int n_in,
                              void* d_out, int out_size, void* d_ws, size_t ws_size,
                              hipStream_t stream) {
    const float* self_v  = (const float*)d_in[0];   // [6400,512]
    const float* neigh_v = (const float*)d_in[1];   // [204800,512]
    const float* W1      = (const float*)d_in[2];   // [512,512]
    const float* b1      = (const float*)d_in[3];   // [512]
    const int*   miter   = (const int*)d_in[4];
    float* out = (float*)d_out;

    const int sites = in_sizes[0] / D_DIM;          // 6400
    const int nrows = in_sizes[1] / D_DIM;          // 204800

    short* s  = (short*)d_ws;                       // [sites,512] bf16
    short* Wb = s + (size_t)sites * D_DIM;          // [512,512] bf16

    wconv<<<dim3(D_DIM * D_DIM / (256 * 8)), dim3(256), 0, stream>>>(W1, Wb);
    gemm_route<false><<<dim3(sites / BM), dim3(256), 0, stream>>>(
        self_v, Wb, b1, s, nullptr, nullptr, nullptr);
    gemm_route<true><<<dim3(nrows / BM), dim3(256), 0, stream>>>(
        neigh_v, Wb, b1, nullptr, s, miter, out);
}

// Round 17
// 247.068 us; speedup vs baseline: 1.3547x; 1.0102x over previous
//
#include <hip/hip_runtime.h>
#include <hip/hip_bf16.h>

// B=128, N=50, NB=32, K=8, H=64, D=512. sites=6400, neighbor rows=204800.
// Fused: per block, 64 neighbor rows (=2 sites) GEMM (bf16 MFMA) into LDS zbuf
// (f16), then 3 routing iterations in-block, write fp32 out.
// Pipeline: r8-verified single-type global_load_lds ledger, vmcnt(10) counted.
// This round: routing datapath in f16 + v_dot2_f32_f16 (2 MAC/instr, no
// unpack) — the only contained lever not yet isolated (r6 bundled it with a
// broken pipeline). GEMM/sync structure byte-identical to the verified base.

#define D_DIM 512
#define BM 64
#define BK 32
#define KSTEPS 16

typedef __attribute__((ext_vector_type(8))) short short8;
typedef __attribute__((ext_vector_type(4))) float f32x4;
typedef _Float16 fp16_t;
typedef __attribute__((ext_vector_type(2))) _Float16 h2v;
typedef __attribute__((ext_vector_type(4))) _Float16 h4v;
typedef __attribute__((ext_vector_type(8))) _Float16 h8v;

static __device__ __forceinline__ short f2bf(float f) {
    __bf16 b = (__bf16)f;
    return __builtin_bit_cast(short, b);
}
static __device__ __forceinline__ void gload_lds16(const void* g, void* l) {
    __builtin_amdgcn_global_load_lds(
        (const __attribute__((address_space(1))) void*)g,
        (__attribute__((address_space(3))) void*)l, 16, 0, 0);
}

#if __has_builtin(__builtin_amdgcn_fdot2)
static __device__ __forceinline__ float fdot2(h2v a, h2v b, float c) {
    return __builtin_amdgcn_fdot2(a, b, c, false);
}
#else
static __device__ __forceinline__ float fdot2(h2v a, h2v b, float c) {
    return fmaf((float)a[0], (float)b[0], fmaf((float)a[1], (float)b[1], c));
}
#endif

__global__ __launch_bounds__(256) void wconv(const float* __restrict__ W,
                                             short* __restrict__ Wb) {
    const int i = (blockIdx.x * 256 + threadIdx.x) * 8;
    const float4 v0 = *reinterpret_cast<const float4*>(W + i);
    const float4 v1 = *reinterpret_cast<const float4*>(W + i + 4);
    short8 o;
    o[0] = f2bf(v0.x); o[1] = f2bf(v0.y); o[2] = f2bf(v0.z); o[3] = f2bf(v0.w);
    o[4] = f2bf(v1.x); o[5] = f2bf(v1.y); o[6] = f2bf(v1.z); o[7] = f2bf(v1.w);
    *reinterpret_cast<short8*>(Wb + i) = o;
}

// 256 threads = 4 waves; wave w -> 64 rows x cols [128w,128w+128).
// lAf32[2]: [64][32] f32 (8 KB each) via DMA; lB[2]: [512][32] bf16 (32 KB each).
template <bool FUSED>
__global__ __launch_bounds__(256, 2) void gemm_route(
    const float* __restrict__ A,     // [R,512] fp32
    const short* __restrict__ Wb,    // [512,512] bf16
    const float* __restrict__ bias,  // [512]
    fp16_t* __restrict__ Zs,         // !FUSED: s output f16
    const fp16_t* __restrict__ S,    // FUSED: s input f16
    const int* __restrict__ miter_ptr,
    float* __restrict__ out)         // FUSED: [sites,512] fp32
{
    __shared__ __align__(16) char smem[81920];
    float* const lAf32 = (float*)smem;           // [2][2048] f32  (16 KB)
    short* const lB = (short*)(smem + 16384);    // [2][16384] bf16 (64 KB)

    const int t = threadIdx.x;
    const int lane = t & 63;
    const int wid = t >> 6;
    const size_t row0 = (size_t)blockIdx.x * BM;
    const int wc = wid * 128;

    const int cb = wc + (lane & 15);
    float bcol[8];
    #pragma unroll
    for (int n = 0; n < 8; ++n) bcol[n] = bias[cb + n * 16];
    int miter = 0;
    if (FUSED) miter = *miter_ptr;

    // 10 DMAs per wave per step: 8 B-chunks + 2 A-chunks (1024 B each).
    auto stage = [&](int step, int buf) {
        const int k0 = (step < KSTEPS ? step : 0) * BK;
        #pragma unroll
        for (int i = 0; i < 8; ++i) {            // B: chunk = 16 rows x 64 B
            const int c = wid * 8 + i;
            const int r = c * 16 + (lane >> 2);
            const int g = ((lane & 3) - (r >> 1)) & 3;
            gload_lds16(Wb + (size_t)r * D_DIM + k0 + g * 8,
                        lB + buf * 16384 + c * 512);
        }
        #pragma unroll
        for (int i = 0; i < 2; ++i) {            // A: chunk = 8 rows x 128 B
            const int c = wid * 2 + i;
            const int r = c * 8 + (lane >> 3);
            const int g = ((lane & 7) - 2 * (r & 3)) & 7;
            gload_lds16(A + (row0 + r) * D_DIM + k0 + g * 4,
                        lAf32 + buf * 2048 + c * 256);
        }
    };

    f32x4 acc[4][8] = {};
    auto compute = [&](int buf) {
        const int q = lane >> 4;                 // k 16B-slot pair index
        short8 af[4], bfr[8];
        #pragma unroll
        for (int m = 0; m < 4; ++m) {
            const int r = m * 16 + (lane & 15);
            const float* ap = lAf32 + buf * 2048 + r * 32 + ((q + (r & 3)) & 3) * 8;
            const f32x4 a0 = *reinterpret_cast<const f32x4*>(ap);
            const f32x4 a1 = *reinterpret_cast<const f32x4*>(ap + 4);
            short8 f;
            f[0] = f2bf(a0[0]); f[1] = f2bf(a0[1]);
            f[2] = f2bf(a0[2]); f[3] = f2bf(a0[3]);
            f[4] = f2bf(a1[0]); f[5] = f2bf(a1[1]);
            f[6] = f2bf(a1[2]); f[7] = f2bf(a1[3]);
            af[m] = f;
        }
        #pragma unroll
        for (int n = 0; n < 8; ++n) {
            const int r = wc + n * 16 + (lane & 15);
            bfr[n] = *reinterpret_cast<const short8*>(
                lB + buf * 16384 + r * 32 + ((q + (r >> 1)) & 3) * 8);
        }
        #pragma unroll
        for (int m = 0; m < 4; ++m)
            #pragma unroll
            for (int n = 0; n < 8; ++n)
                acc[m][n] = __builtin_amdgcn_mfma_f32_16x16x32_bf16(
                    af[m], bfr[n], acc[m][n], 0, 0, 0);
    };

    // ---- pipeline: counted vmcnt, single op type, loads fly across barriers
    stage(0, 0);
    stage(1, 1);
    asm volatile("s_waitcnt vmcnt(10)" ::: "memory");   // stage0 (+scalars) done
    __builtin_amdgcn_s_barrier();
    #pragma unroll
    for (int tk = 0; tk < KSTEPS; ++tk) {
        compute(tk & 1);
        asm volatile("s_waitcnt lgkmcnt(0)" ::: "memory");  // reads consumed
        __builtin_amdgcn_s_barrier();                       // buf tk&1 free
        stage(tk + 2, tk & 1);                              // overwrite it
        asm volatile("s_waitcnt vmcnt(10)" ::: "memory");   // stage(tk+1) done
        __builtin_amdgcn_s_barrier();                       // visible to all
    }
    asm volatile("s_waitcnt vmcnt(0)" ::: "memory");        // drain tail junk
    __builtin_amdgcn_s_barrier();

    // ---- epilogue: bias + ReLU + l2norm per 64-col group; z as f16.
    fp16_t* const zbuf = (fp16_t*)(smem + 16384);   // aliases lB (free now)
    #pragma unroll
    for (int m = 0; m < 4; ++m) {
        #pragma unroll
        for (int r = 0; r < 4; ++r) {
            float v[8];
            float ssa = 0.0f, ssb = 0.0f;
            #pragma unroll
            for (int n = 0; n < 4; ++n) {
                v[n] = fmaxf(acc[m][n][r] + bcol[n], 0.0f);
                ssa = fmaf(v[n], v[n], ssa);
            }
            #pragma unroll
            for (int n = 4; n < 8; ++n) {
                v[n] = fmaxf(acc[m][n][r] + bcol[n], 0.0f);
                ssb = fmaf(v[n], v[n], ssb);
            }
            ssa += __shfl_xor(ssa, 1); ssb += __shfl_xor(ssb, 1);
            ssa += __shfl_xor(ssa, 2); ssb += __shfl_xor(ssb, 2);
            ssa += __shfl_xor(ssa, 4); ssb += __shfl_xor(ssb, 4);
            ssa += __shfl_xor(ssa, 8); ssb += __shfl_xor(ssb, 8);
            const float inva = 1.0f / fmaxf(sqrtf(ssa), 1e-12f);
            const float invb = 1.0f / fmaxf(sqrtf(ssb), 1e-12f);
            const int orow = m * 16 + (lane >> 4) * 4 + r;   // 0..63
            if (FUSED) {
                #pragma unroll
                for (int n = 0; n < 4; ++n)
                    zbuf[orow * D_DIM + cb + n * 16] = (fp16_t)(v[n] * inva);
                #pragma unroll
                for (int n = 4; n < 8; ++n)
                    zbuf[orow * D_DIM + cb + n * 16] = (fp16_t)(v[n] * invb);
            } else {
                #pragma unroll
                for (int n = 0; n < 4; ++n)
                    Zs[(row0 + orow) * D_DIM + cb + n * 16] = (fp16_t)(v[n] * inva);
                #pragma unroll
                for (int n = 4; n < 8; ++n)
                    Zs[(row0 + orow) * D_DIM + cb + n * 16] = (fp16_t)(v[n] * invb);
            }
        }
    }

    if (!FUSED) return;
    __syncthreads();   // zbuf complete

    // ---- routing: 2 sites/block, 128 threads each; f16 z/u + fdot2 dots.
    fp16_t* const uh = (fp16_t*)smem;               // [2][512] f16 (aliases lAf32)
    float* const ppb = (float*)(smem + 4096);       // [2][256] f32
    const int tt = t & 127;
    const int ssid = t >> 7;
    const size_t site = (size_t)blockIdx.x * 2 + ssid;
    fp16_t* const u_ = uh + ssid * D_DIM;
    float* const p_ = ppb + ssid * 256;
    const fp16_t* const zr = zbuf + ssid * 32 * D_DIM;

    const int e = tt * 4;
    const int go = tt >> 4;                  // capsule group of owned elems
    const h4v sv = *reinterpret_cast<const h4v*>(S + site * D_DIM + e);
    const float s0 = (float)sv[0], s1 = (float)sv[1];
    const float s2 = (float)sv[2], s3 = (float)sv[3];

    float v0, v1, v2, v3;
    {   // iteration 0: p uniform 1/8
        float a0 = 0, a1 = 0, a2 = 0, a3 = 0;
        for (int m = 0; m < 32; ++m) {
            const h4v z = *reinterpret_cast<const h4v*>(zr + m * D_DIM + e);
            a0 += (float)z[0]; a1 += (float)z[1];
            a2 += (float)z[2]; a3 += (float)z[3];
        }
        v0 = fmaf(a0, 0.125f, s0); v1 = fmaf(a1, 0.125f, s1);
        v2 = fmaf(a2, 0.125f, s2); v3 = fmaf(a3, 0.125f, s3);
    }

    const int dm = tt >> 2;                  // neighbor for this thread's dots
    const int ka = (tt & 3) * 2;             // capsule pair
    const fp16_t* const za = zr + dm * D_DIM + ka * 64;
    const fp16_t* const ua = u_ + ka * 64;

    for (int it = 1; it < miter; ++it) {
        // normalize u per 64-group (16-thread shfl groups, wave-aligned)
        float ssum = v0 * v0 + v1 * v1 + v2 * v2 + v3 * v3;
        ssum += __shfl_xor(ssum, 1);
        ssum += __shfl_xor(ssum, 2);
        ssum += __shfl_xor(ssum, 4);
        ssum += __shfl_xor(ssum, 8);
        const float inv = 1.0f / fmaxf(sqrtf(ssum), 1e-12f);
        v0 *= inv; v1 *= inv; v2 *= inv; v3 *= inv;
        h4v uw; uw[0] = (fp16_t)v0; uw[1] = (fp16_t)v1;
        uw[2] = (fp16_t)v2; uw[3] = (fp16_t)v3;
        *reinterpret_cast<h4v*>(u_ + e) = uw;
        __syncthreads();

        // dots p[dm][ka], p[dm][ka+1] via v_dot2_f32_f16; staggered octets
        float da = 0.0f, db = 0.0f;
        #pragma unroll
        for (int j = 0; j < 8; ++j) {
            const int jj = ((j + (tt & 7)) & 7) * 8;
            const h8v zA = *reinterpret_cast<const h8v*>(za + jj);
            const h8v uA = *reinterpret_cast<const h8v*>(ua + jj);
            const h8v zB = *reinterpret_cast<const h8v*>(za + 64 + jj);
            const h8v uB = *reinterpret_cast<const h8v*>(ua + 64 + jj);
            da = fdot2(__builtin_shufflevector(zA, zA, 0, 1),
                       __builtin_shufflevector(uA, uA, 0, 1), da);
            da = fdot2(__builtin_shufflevector(zA, zA, 2, 3),
                       __builtin_shufflevector(uA, uA, 2, 3), da);
            da = fdot2(__builtin_shufflevector(zA, zA, 4, 5),
                       __builtin_shufflevector(uA, uA, 4, 5), da);
            da = fdot2(__builtin_shufflevector(zA, zA, 6, 7),
                       __builtin_shufflevector(uA, uA, 6, 7), da);
            db = fdot2(__builtin_shufflevector(zB, zB, 0, 1),
                       __builtin_shufflevector(uB, uB, 0, 1), db);
            db = fdot2(__builtin_shufflevector(zB, zB, 2, 3),
                       __builtin_shufflevector(uB, uB, 2, 3), db);
            db = fdot2(__builtin_shufflevector(zB, zB, 4, 5),
                       __builtin_shufflevector(uB, uB, 4, 5), db);
            db = fdot2(__builtin_shufflevector(zB, zB, 6, 7),
                       __builtin_shufflevector(uB, uB, 6, 7), db);
        }
        // softmax over 8 k (4 threads x 2 vals)
        float mx = fmaxf(da, db);
        mx = fmaxf(mx, __shfl_xor(mx, 1));
        mx = fmaxf(mx, __shfl_xor(mx, 2));
        const float ea = __expf(da - mx), eb = __expf(db - mx);
        float sm_ = ea + eb;
        sm_ += __shfl_xor(sm_, 1);
        sm_ += __shfl_xor(sm_, 2);
        const float rs = 1.0f / sm_;
        *reinterpret_cast<float2*>(p_ + dm * 8 + ka) = make_float2(ea * rs, eb * rs);
        __syncthreads();

        // u = s + sum_m z[m]*p[m, go]
        float a0 = 0, a1 = 0, a2 = 0, a3 = 0;
        for (int m = 0; m < 32; ++m) {
            const h4v z = *reinterpret_cast<const h4v*>(zr + m * D_DIM + e);
            const float pm = p_[m * 8 + go];
            a0 = fmaf((float)z[0], pm, a0); a1 = fmaf((float)z[1], pm, a1);
            a2 = fmaf((float)z[2], pm, a2); a3 = fmaf((float)z[3], pm, a3);
        }
        v0 = s0 + a0; v1 = s1 + a1; v2 = s2 + a2; v3 = s3 + a3;
        // next p_ write is after next norm's barrier -> safe
    }

    *reinterpret_cast<float4*>(out + site * D_DIM + e) =
        make_float4(fmaxf(v0, 0.0f), fmaxf(v1, 0.0f),
                    fmaxf(v2, 0.0f), fmaxf(v3, 0.0f));
}

extern "C" void kernel_launch(void* const* d_in, const int* in_sizes, int n_in,
                              void* d_out, int out_size, void* d_ws, size_t ws_size,
                              hipStream_t stream) {
    const float* self_v  = (const float*)d_in[0];   // [6400,512]
    const float* neigh_v = (const float*)d_in[1];   // [204800,512]
    const float* W1      = (const float*)d_in[2];   // [512,512]
    const float* b1      = (const float*)d_in[3];   // [512]
    const int*   miter   = (const int*)d_in[4];
    float* out = (float*)d_out;

    const int sites = in_sizes[0] / D_DIM;          // 6400
    const int nrows = in_sizes[1] / D_DIM;          // 204800

    fp16_t* s = (fp16_t*)d_ws;                      // [sites,512] f16
    short* Wb = (short*)(s + (size_t)sites * D_DIM);// [512,512] bf16

    wconv<<<dim3(D_DIM * D_DIM / (256 * 8)), dim3(256), 0, stream>>>(W1, Wb);
    gemm_route<false><<<dim3(sites / BM), dim3(256), 0, stream>>>(
        self_v, Wb, b1, s, nullptr, nullptr, nullptr);
    gemm_route<true><<<dim3(nrows / BM), dim3(256), 0, stream>>>(
        neigh_v, Wb, b1, nullptr, s, miter, out);
}